// Round 18
// baseline (486.871 us; speedup 1.0000x reference)
//
#include <hip/hip_runtime.h>
#include <math.h>

// CrossAttention (N=8, Lq=1024, Lk=4096, D=1024), fp32 in/out.
// scores = Q''*input^T (+row const); Q'' = query*(Wq^T*Wk) + bq*Wk; bk cancels.
// V = unprojected input. out = (P*V)*Wo^T + bo.
// R14: score path single-f16 (absmax 0.0898 < 0.1006). R17: XCD swizzle on S/PV.
// R18: KU=2 k-unroll on S/PV/out-proj GEMMs — two 32-k tiles staged per LDS
// buffer, computed between ONE barrier pair (barrier count halves; MFMA order
// over k unchanged -> bitwise-identical results). LDS 64 KB -> still 2 blk/CU.

using short8 = __attribute__((ext_vector_type(8))) short;
using f32x4  = __attribute__((ext_vector_type(4))) float;

__device__ inline ushort f2h_u(float f) {
    _Float16 h = (_Float16)f;
    return __builtin_bit_cast(ushort, h);
}
__device__ inline float h2f(ushort u) {
    return (float)__builtin_bit_cast(_Float16, u);
}
__device__ inline void split2h(float x, ushort& h, ushort& l) {
    const ushort hu = f2h_u(x);
    h = hu;
    l = f2h_u(x - h2f(hu));
}

// b'[j] = sum_d bq[d] * Wk[d][j]
__global__ __launch_bounds__(256)
void bias_proj_k(const float* __restrict__ bq, const float* __restrict__ Wk,
                 float* __restrict__ bp)
{
    const int j = blockIdx.x * 256 + threadIdx.x;
    float s = 0.f;
    for (int d = 0; d < 1024; ++d) s = fmaf(bq[d], Wk[d * 1024 + j], s);
    bp[j] = s;
}

// fp32 -> f16 hi (+optional lo), grid-stride over float4s
__global__ __launch_bounds__(256)
void split_k(const float* __restrict__ x, ushort* __restrict__ hi,
             ushort* __restrict__ lo, int n4)
{
    for (int i = blockIdx.x * 256 + threadIdx.x; i < n4; i += gridDim.x * 256) {
        const float4 v = reinterpret_cast<const float4*>(x)[i];
        ushort4 h, l;
        split2h(v.x, h.x, l.x); split2h(v.y, h.y, l.y);
        split2h(v.z, h.z, l.z); split2h(v.w, h.w, l.w);
        reinterpret_cast<ushort4*>(hi)[i] = h;
        if (lo) reinterpret_cast<ushort4*>(lo)[i] = l;
    }
}

// out[c][r] = in[r][c] with f16 hi/lo split. grid (C/32, R/32).
__global__ __launch_bounds__(256)
void trans_split_k(const float* __restrict__ in, ushort* __restrict__ oh,
                   ushort* __restrict__ ol, int R, int C)
{
    __shared__ float ts[32][33];
    const int t = threadIdx.x, tx = t & 31, tg = t >> 5;
    const int r0 = blockIdx.y * 32, c0 = blockIdx.x * 32;
    #pragma unroll
    for (int i = 0; i < 4; ++i) {
        const int r = tg * 4 + i;
        ts[r][tx] = in[(size_t)(r0 + r) * C + c0 + tx];
    }
    __syncthreads();
    #pragma unroll
    for (int i = 0; i < 4; ++i) {
        const int c = tg * 4 + i;
        ushort h, l; split2h(ts[tx][c], h, l);
        const size_t o = (size_t)(c0 + c) * R + r0 + tx;
        oh[o] = h;
        if (ol) ol[o] = l;
    }
}

// Fused: read input [LI][D] fp32 once -> ih f16 [LI][D] + VT f16 [D][LI].
// grid (D/32, LI/32, NB), block 256.
__global__ __launch_bounds__(256)
void prep_input_k(const float* __restrict__ in, ushort* __restrict__ ih,
                  ushort* __restrict__ vt, int LI, int D, long long bs)
{
    __shared__ float ts[32][33];
    const int t = threadIdx.x;
    const int tx8 = t & 7, ty = t >> 3;
    const int r0 = blockIdx.y * 32, c0 = blockIdx.x * 32;
    const long long z = blockIdx.z;
    in += z * bs; ih += z * bs; vt += z * bs;

    const float4 v = *reinterpret_cast<const float4*>(
        &in[(size_t)(r0 + ty) * D + c0 + tx8 * 4]);
    ushort4 h;
    h.x = f2h_u(v.x); h.y = f2h_u(v.y); h.z = f2h_u(v.z); h.w = f2h_u(v.w);
    *reinterpret_cast<ushort4*>(&ih[(size_t)(r0 + ty) * D + c0 + tx8 * 4]) = h;
    ts[ty][tx8 * 4 + 0] = v.x; ts[ty][tx8 * 4 + 1] = v.y;
    ts[ty][tx8 * 4 + 2] = v.z; ts[ty][tx8 * 4 + 3] = v.w;
    __syncthreads();
    const int tx = t & 31, tg = t >> 5;
    #pragma unroll
    for (int i = 0; i < 4; ++i) {
        const int c = tg * 4 + i;
        vt[(size_t)(c0 + c) * LI + r0 + tx] = f2h_u(ts[tx][c]);
    }
}

// masked softmax over 4096-wide fp32 rows -> f16 P. grid (LQ, NB).
__global__ __launch_bounds__(256)
void softmax_f16_k(const float* __restrict__ S, const int* __restrict__ mask,
                   ushort* __restrict__ P)
{
    const int t = threadIdx.x;
    const size_t row = (size_t)blockIdx.y * gridDim.x + blockIdx.x;
    const float* srow = S + row * 4096;
    ushort* prow = P + row * 4096;
    mask += (size_t)blockIdx.y * 4096;
    float4 v[4];
    float lmax = -INFINITY;
    #pragma unroll
    for (int c = 0; c < 4; ++c) {
        const int idx = c * 1024 + t * 4;
        v[c] = *reinterpret_cast<const float4*>(&srow[idx]);
        const int4 m4 = *reinterpret_cast<const int4*>(&mask[idx]);
        if (m4.x) v[c].x = -INFINITY;
        if (m4.y) v[c].y = -INFINITY;
        if (m4.z) v[c].z = -INFINITY;
        if (m4.w) v[c].w = -INFINITY;
        lmax = fmaxf(lmax, fmaxf(fmaxf(v[c].x, v[c].y), fmaxf(v[c].z, v[c].w)));
    }
    #pragma unroll
    for (int off = 32; off > 0; off >>= 1)
        lmax = fmaxf(lmax, __shfl_xor(lmax, off));
    __shared__ float redm[4], reds[4];
    if ((t & 63) == 0) redm[t >> 6] = lmax;
    __syncthreads();
    const float bmax = fmaxf(fmaxf(redm[0], redm[1]), fmaxf(redm[2], redm[3]));
    float lsum = 0.f;
    #pragma unroll
    for (int c = 0; c < 4; ++c) {
        v[c].x = __expf(v[c].x - bmax);
        v[c].y = __expf(v[c].y - bmax);
        v[c].z = __expf(v[c].z - bmax);
        v[c].w = __expf(v[c].w - bmax);
        lsum += (v[c].x + v[c].y) + (v[c].z + v[c].w);
    }
    #pragma unroll
    for (int off = 32; off > 0; off >>= 1)
        lsum += __shfl_xor(lsum, off);
    if ((t & 63) == 0) reds[t >> 6] = lsum;
    __syncthreads();
    const float Z = (reds[0] + reds[1]) + (reds[2] + reds[3]);
    const float inv = 1.0f / Z;
    #pragma unroll
    for (int c = 0; c < 4; ++c) {
        const int idx = c * 1024 + t * 4;
        ushort4 o;
        o.x = f2h_u(v[c].x * inv); o.y = f2h_u(v[c].y * inv);
        o.z = f2h_u(v[c].z * inv); o.w = f2h_u(v[c].w * inv);
        *reinterpret_cast<ushort4*>(&prow[idx]) = o;
    }
}

// ---------------------------------------------------------------------------
// 128^2 MFMA GEMM (proven R5-R17): C = A_eff * B_eff^T, B stored [N][K].
// AS/BS in {1,2}: operand hi (+lo). OUTMODE: 0 fp32, 1 f16, 2 f16 pair.
// SWZ: 1D grid with bijective XCD swizzle (nwg % 8 == 0).
// KU: k-tiles (32 wide) staged per LDS buffer; barriers per K = K/(32*KU).
// ---------------------------------------------------------------------------
template<int TR>
__device__ inline void stage_one(const ushort* __restrict__ g, int ld, int r0,
                                 int k0, ushort* ldsbase, int w, int l)
{
    constexpr int ISS = TR / 64;
    #pragma unroll
    for (int q = 0; q < ISS; ++q) {
        const int idx = (w * ISS + q) * 64 + l;
        const int row = idx >> 2;
        const int gslot = (idx & 3) ^ ((idx >> 3) & 3);
        const ushort* src = g + (size_t)(r0 + row) * ld + k0 + gslot * 8;
        ushort* dst = ldsbase + (size_t)(w * ISS + q) * 512;
        __builtin_amdgcn_global_load_lds(
            (const __attribute__((address_space(1))) void*)src,
            (__attribute__((address_space(3))) void*)dst, 16, 0, 0);
    }
}

template<int BM, int BN, int AS, int BS, int OUTMODE, bool SWZ = false, int KU = 1>
__global__ __launch_bounds__(256, 2)
void mfma_gemm_k(const ushort* __restrict__ Ah, const ushort* __restrict__ Al,
                 const ushort* __restrict__ Bh, const ushort* __restrict__ Bl,
                 const float* __restrict__ bias,
                 float* __restrict__ Cf, ushort* __restrict__ Ch,
                 ushort* __restrict__ Cl,
                 int K, int lda, int ldb, int ldc,
                 long long bsA, long long bsB, long long bsC,
                 int nx, int ny)
{
    constexpr int FM = BM / 32, FN = BN / 32;
    constexpr int AU = AS * BM * 32;
    constexpr int TILE_1 = AU + BS * BN * 32;   // ushorts per 32-k tile
    __shared__ __align__(16) ushort lds[2][KU * TILE_1];

    int bx, by;
    long long zb;
    if constexpr (SWZ) {
        const int nwg = gridDim.x;
        const int q8 = nwg >> 3;
        const int swz = (blockIdx.x & 7) * q8 + (blockIdx.x >> 3);
        const int pt = nx * ny;
        const int z = swz / pt;
        const int r = swz - z * pt;
        by = r / nx; bx = r - by * nx;
        zb = z;
    } else {
        bx = blockIdx.x; by = blockIdx.y; zb = blockIdx.z;
    }

    Ah += zb * bsA; Bh += zb * bsB;
    if constexpr (AS == 2) Al += zb * bsA;
    if constexpr (BS == 2) Bl += zb * bsB;

    const int t = threadIdx.x;
    const int l = t & 63, w = t >> 6;
    const int lr = l & 15, ls = l >> 4;
    const int i0 = by * BM, j0 = bx * BN;
    const int wr = (w >> 1) * (BM / 2), wc = (w & 1) * (BN / 2);
    const int swu = (ls ^ ((lr >> 1) & 3)) * 8;

    f32x4 acc[FM][FN] = {};
    const int nk = (K >> 5) / KU;

    auto stage = [&](int buf, int kt) {
        #pragma unroll
        for (int ku = 0; ku < KU; ++ku) {
            const int k0 = (kt * KU + ku) << 5;
            ushort* base = &lds[buf][ku * TILE_1];
            stage_one<BM>(Ah, lda, i0, k0, base, w, l);
            if constexpr (AS == 2) stage_one<BM>(Al, lda, i0, k0, base + BM * 32, w, l);
            stage_one<BN>(Bh, ldb, j0, k0, base + AU, w, l);
            if constexpr (BS == 2) stage_one<BN>(Bl, ldb, j0, k0, base + AU + BN * 32, w, l);
        }
    };

    stage(0, 0);
    for (int kt = 0; kt < nk; ++kt) {
        __syncthreads();
        const int buf = kt & 1;
        if (kt + 1 < nk) stage(buf ^ 1, kt + 1);

        #pragma unroll
        for (int ku = 0; ku < KU; ++ku) {
            const ushort* base = &lds[buf][ku * TILE_1];

            short8 ah[FM], bh[FN];
            #pragma unroll
            for (int fi = 0; fi < FM; ++fi)
                ah[fi] = *reinterpret_cast<const short8*>(
                    base + (wr + fi * 16 + lr) * 32 + swu);
            #pragma unroll
            for (int fj = 0; fj < FN; ++fj)
                bh[fj] = *reinterpret_cast<const short8*>(
                    base + AU + (wc + fj * 16 + lr) * 32 + swu);

            #pragma unroll
            for (int fi = 0; fi < FM; ++fi)
                #pragma unroll
                for (int fj = 0; fj < FN; ++fj)
                    acc[fi][fj] = __builtin_amdgcn_mfma_f32_16x16x32_f16(
                        ah[fi], bh[fj], acc[fi][fj], 0, 0, 0);

            if constexpr (BS == 2) {
                short8 bl[FN];
                #pragma unroll
                for (int fj = 0; fj < FN; ++fj)
                    bl[fj] = *reinterpret_cast<const short8*>(
                        base + AU + BN * 32 + (wc + fj * 16 + lr) * 32 + swu);
                #pragma unroll
                for (int fi = 0; fi < FM; ++fi)
                    #pragma unroll
                    for (int fj = 0; fj < FN; ++fj)
                        acc[fi][fj] = __builtin_amdgcn_mfma_f32_16x16x32_f16(
                            ah[fi], bl[fj], acc[fi][fj], 0, 0, 0);
            }
            if constexpr (AS == 2) {
                short8 al[FM];
                #pragma unroll
                for (int fi = 0; fi < FM; ++fi)
                    al[fi] = *reinterpret_cast<const short8*>(
                        base + BM * 32 + (wr + fi * 16 + lr) * 32 + swu);
                #pragma unroll
                for (int fi = 0; fi < FM; ++fi)
                    #pragma unroll
                    for (int fj = 0; fj < FN; ++fj)
                        acc[fi][fj] = __builtin_amdgcn_mfma_f32_16x16x32_f16(
                            al[fi], bh[fj], acc[fi][fj], 0, 0, 0);
            }
        }
    }

    #pragma unroll
    for (int fj = 0; fj < FN; ++fj) {
        const int gc = j0 + wc + fj * 16 + lr;
        const float bv = bias ? bias[gc] : 0.0f;
        #pragma unroll
        for (int fi = 0; fi < FM; ++fi) {
            const int gr = i0 + wr + fi * 16 + ls * 4;
            #pragma unroll
            for (int r = 0; r < 4; ++r) {
                const float v = acc[fi][fj][r] + bv;
                const size_t o = zb * bsC + (size_t)(gr + r) * ldc + gc;
                if constexpr (OUTMODE == 0) {
                    Cf[o] = v;
                } else if constexpr (OUTMODE == 1) {
                    Ch[o] = f2h_u(v);
                } else {
                    ushort h, lo2; split2h(v, h, lo2);
                    Ch[o] = h;
                    Cl[o] = lo2;
                }
            }
        }
    }
}

// ---------------------------------------------------------------------------
extern "C" void kernel_launch(void* const* d_in, const int* in_sizes, int n_in,
                              void* d_out, int out_size, void* d_ws, size_t ws_size,
                              hipStream_t stream)
{
    (void)in_sizes; (void)n_in; (void)out_size;
    const int NB = 8, LQ = 1024, LI = 4096, D = 1024;
    const long long sQD = (long long)LQ * D;   // 1M
    const long long sID = (long long)LI * D;   // 4M
    const long long sQI = (long long)LQ * LI;  // 4M

    const float* query = (const float*)d_in[0];
    const float* input = (const float*)d_in[1];
    const int* mask = (const int*)d_in[2];   // bool -> int32 on device
    const float* Wq = (const float*)d_in[3];
    const float* bq = (const float*)d_in[4];
    const float* Wk = (const float*)d_in[5];
    /* d_in[6] = bk: cancels in softmax */
    const float* Wo = (const float*)d_in[7];
    const float* bo = (const float*)d_in[8];
    float* out = (float*)d_out;

    dim3 blk(256);

    char* p = (char*)d_ws;
    auto alloc = [&](size_t bytes) {
        char* r = p; p += (bytes + 255) & ~(size_t)255; return r;
    };
    // head buffers
    ushort* qh   = (ushort*)alloc((size_t)NB * sQD * 2);  // query f16
    ushort* WqTh = (ushort*)alloc((size_t)D * D * 2);
    ushort* WqTl = (ushort*)alloc((size_t)D * D * 2);
    ushort* WkTh = (ushort*)alloc((size_t)D * D * 2);
    ushort* WkTl = (ushort*)alloc((size_t)D * D * 2);
    ushort* WTh  = (ushort*)alloc((size_t)D * D * 2);     // W'^T hi/lo
    ushort* WTl  = (ushort*)alloc((size_t)D * D * 2);
    float*  bp   = (float*) alloc((size_t)D * 4);
    ushort* Qh   = (ushort*)alloc((size_t)NB * sQD * 2);  // Q'' f16 (single)
    ushort* Ob   = (ushort*)alloc((size_t)NB * sQD * 2);  // O f16
    ushort* Wob  = (ushort*)alloc((size_t)D * D * 2);     // Wo f16
    char* tail = p;

    // full-batch tail
    ushort* inh = (ushort*)alloc((size_t)NB * sID * 2);   // input f16 [LI][D]
    ushort* VT  = (ushort*)alloc((size_t)NB * sID * 2);   // V^T f16 [D][LI]
    float*  S   = (float*) alloc((size_t)NB * sQI * 4);
    ushort* Pb  = (ushort*)alloc((size_t)NB * sQI * 2);
    const bool full = (size_t)(p - (char*)d_ws) <= ws_size;
    if (!full) {
        p = tail;
        inh = (ushort*)alloc((size_t)sID * 2);
        VT  = (ushort*)alloc((size_t)sID * 2);
        S   = (float*) alloc((size_t)sQI * 4);
        Pb  = (ushort*)alloc((size_t)sQI * 2);
    }

    // ---- head ----
    trans_split_k<<<dim3(32, 32), blk, 0, stream>>>(Wq, WqTh, WqTl, D, D);
    trans_split_k<<<dim3(32, 32), blk, 0, stream>>>(Wk, WkTh, WkTl, D, D);
    bias_proj_k<<<dim3(4), blk, 0, stream>>>(bq, Wk, bp);
    // W'^T = Wk^T @ (Wq^T)^T, split-2 both sides, hi/lo out
    mfma_gemm_k<64, 64, 2, 2, 2><<<dim3(16, 16, 1), blk, 0, stream>>>(
        WkTh, WkTl, WqTh, WqTl, nullptr, nullptr, WTh, WTl, D, D, D, D, 0, 0, 0, 0, 0);
    split_k<<<dim3(2048), blk, 0, stream>>>(query, qh, nullptr, NB * (int)sQD / 4);
    split_k<<<dim3(1024), blk, 0, stream>>>(Wo, Wob, nullptr, D * D / 4);
    // Q'' = query @ W' + b'  (A single, B hi/lo; f16 out)
    mfma_gemm_k<128, 128, 1, 2, 1><<<dim3(D / 128, NB * LQ / 128, 1), blk, 0, stream>>>(
        qh, nullptr, WTh, WTl, bp, nullptr, Qh, nullptr, D, D, D, D, 0, 0, 0, 0, 0);

    if (full) {
        prep_input_k<<<dim3(D / 32, LI / 32, NB), blk, 0, stream>>>(
            input, inh, VT, LI, D, sID);
        // S = Q'' @ input^T  (single f16, K=1024; fp32 out; swizzle; KU=2)
        mfma_gemm_k<128, 128, 1, 1, 0, true, 2><<<dim3((LI/128)*(LQ/128)*NB), blk, 0, stream>>>(
            Qh, nullptr, inh, nullptr, nullptr, S, nullptr, nullptr,
            D, D, D, LI, sQD, sID, sQI, LI / 128, LQ / 128);
        softmax_f16_k<<<dim3(LQ, NB), blk, 0, stream>>>(S, mask, Pb);
        // O = P @ V  (plain f16; swizzle; KU=2)
        mfma_gemm_k<128, 128, 1, 1, 1, true, 2><<<dim3((D/128)*(LQ/128)*NB), blk, 0, stream>>>(
            Pb, nullptr, VT, nullptr, nullptr, nullptr, Ob, nullptr,
            LI, LI, LI, D, sQI, sID, sQD, D / 128, LQ / 128);
    } else {
        for (int b = 0; b < NB; ++b) {
            const float* in_b = input + (size_t)b * sID;
            prep_input_k<<<dim3(D / 32, LI / 32, 1), blk, 0, stream>>>(
                in_b, inh, VT, LI, D, 0);
            mfma_gemm_k<128, 128, 1, 1, 0, false, 2><<<dim3(LI / 128, LQ / 128, 1), blk, 0, stream>>>(
                Qh + (size_t)b * sQD, nullptr, inh, nullptr, nullptr, S, nullptr, nullptr,
                D, D, D, LI, 0, 0, 0, 0, 0);
            softmax_f16_k<<<dim3(LQ, 1), blk, 0, stream>>>(S, mask + (size_t)b * LI, Pb);
            mfma_gemm_k<128, 128, 1, 1, 1, false, 2><<<dim3(D / 128, LQ / 128, 1), blk, 0, stream>>>(
                Pb, nullptr, VT, nullptr, nullptr, nullptr,
                Ob + (size_t)b * sQD, nullptr, LI, LI, LI, D, 0, 0, 0, 0, 0);
        }
    }
    // out = O @ Wo^T + bo (fp32 out; KU=2)
    mfma_gemm_k<128, 128, 1, 1, 0, false, 2><<<dim3(D / 128, NB * LQ / 128, 1), blk, 0, stream>>>(
        Ob, nullptr, Wob, nullptr, bo, out, nullptr, nullptr, D, D, D, D, 0, 0, 0, 0, 0);
}

// Round 19
// 459.868 us; speedup vs baseline: 1.0587x; 1.0587x over previous
//
#include <hip/hip_runtime.h>
#include <math.h>

// CrossAttention (N=8, Lq=1024, Lk=4096, D=1024), fp32 in/out.
// scores = Q''*input^T (+row const); Q'' = query*(Wq^T*Wk) + bq*Wk; bk cancels.
// V = unprojected input. out = (P*V)*Wo^T + bo.
// R14: score path single-f16 (absmax 0.0898 < 0.1006).
// R17: T1 bijective XCD swizzle on the batched S and PV GEMMs.
// R19: revert of R18's KU=2 (regressed: per-barrier drain scales with staged
// bytes, so fewer-but-bigger barriers are net-negative + VGPR/LDS overhead).
// S fp32. P/V/O/Wo f16. All GEMMs on the proven 128^2 template.

using short8 = __attribute__((ext_vector_type(8))) short;
using f32x4  = __attribute__((ext_vector_type(4))) float;

__device__ inline ushort f2h_u(float f) {
    _Float16 h = (_Float16)f;
    return __builtin_bit_cast(ushort, h);
}
__device__ inline float h2f(ushort u) {
    return (float)__builtin_bit_cast(_Float16, u);
}
__device__ inline void split2h(float x, ushort& h, ushort& l) {
    const ushort hu = f2h_u(x);
    h = hu;
    l = f2h_u(x - h2f(hu));
}

// b'[j] = sum_d bq[d] * Wk[d][j]
__global__ __launch_bounds__(256)
void bias_proj_k(const float* __restrict__ bq, const float* __restrict__ Wk,
                 float* __restrict__ bp)
{
    const int j = blockIdx.x * 256 + threadIdx.x;
    float s = 0.f;
    for (int d = 0; d < 1024; ++d) s = fmaf(bq[d], Wk[d * 1024 + j], s);
    bp[j] = s;
}

// fp32 -> f16 hi (+optional lo), grid-stride over float4s
__global__ __launch_bounds__(256)
void split_k(const float* __restrict__ x, ushort* __restrict__ hi,
             ushort* __restrict__ lo, int n4)
{
    for (int i = blockIdx.x * 256 + threadIdx.x; i < n4; i += gridDim.x * 256) {
        const float4 v = reinterpret_cast<const float4*>(x)[i];
        ushort4 h, l;
        split2h(v.x, h.x, l.x); split2h(v.y, h.y, l.y);
        split2h(v.z, h.z, l.z); split2h(v.w, h.w, l.w);
        reinterpret_cast<ushort4*>(hi)[i] = h;
        if (lo) reinterpret_cast<ushort4*>(lo)[i] = l;
    }
}

// out[c][r] = in[r][c] with f16 hi/lo split. grid (C/32, R/32).
__global__ __launch_bounds__(256)
void trans_split_k(const float* __restrict__ in, ushort* __restrict__ oh,
                   ushort* __restrict__ ol, int R, int C)
{
    __shared__ float ts[32][33];
    const int t = threadIdx.x, tx = t & 31, tg = t >> 5;
    const int r0 = blockIdx.y * 32, c0 = blockIdx.x * 32;
    #pragma unroll
    for (int i = 0; i < 4; ++i) {
        const int r = tg * 4 + i;
        ts[r][tx] = in[(size_t)(r0 + r) * C + c0 + tx];
    }
    __syncthreads();
    #pragma unroll
    for (int i = 0; i < 4; ++i) {
        const int c = tg * 4 + i;
        ushort h, l; split2h(ts[tx][c], h, l);
        const size_t o = (size_t)(c0 + c) * R + r0 + tx;
        oh[o] = h;
        if (ol) ol[o] = l;
    }
}

// Fused: read input [LI][D] fp32 once -> ih f16 [LI][D] + VT f16 [D][LI].
// grid (D/32, LI/32, NB), block 256.
__global__ __launch_bounds__(256)
void prep_input_k(const float* __restrict__ in, ushort* __restrict__ ih,
                  ushort* __restrict__ vt, int LI, int D, long long bs)
{
    __shared__ float ts[32][33];
    const int t = threadIdx.x;
    const int tx8 = t & 7, ty = t >> 3;
    const int r0 = blockIdx.y * 32, c0 = blockIdx.x * 32;
    const long long z = blockIdx.z;
    in += z * bs; ih += z * bs; vt += z * bs;

    const float4 v = *reinterpret_cast<const float4*>(
        &in[(size_t)(r0 + ty) * D + c0 + tx8 * 4]);
    ushort4 h;
    h.x = f2h_u(v.x); h.y = f2h_u(v.y); h.z = f2h_u(v.z); h.w = f2h_u(v.w);
    *reinterpret_cast<ushort4*>(&ih[(size_t)(r0 + ty) * D + c0 + tx8 * 4]) = h;
    ts[ty][tx8 * 4 + 0] = v.x; ts[ty][tx8 * 4 + 1] = v.y;
    ts[ty][tx8 * 4 + 2] = v.z; ts[ty][tx8 * 4 + 3] = v.w;
    __syncthreads();
    const int tx = t & 31, tg = t >> 5;
    #pragma unroll
    for (int i = 0; i < 4; ++i) {
        const int c = tg * 4 + i;
        vt[(size_t)(c0 + c) * LI + r0 + tx] = f2h_u(ts[tx][c]);
    }
}

// masked softmax over 4096-wide fp32 rows -> f16 P. grid (LQ, NB).
__global__ __launch_bounds__(256)
void softmax_f16_k(const float* __restrict__ S, const int* __restrict__ mask,
                   ushort* __restrict__ P)
{
    const int t = threadIdx.x;
    const size_t row = (size_t)blockIdx.y * gridDim.x + blockIdx.x;
    const float* srow = S + row * 4096;
    ushort* prow = P + row * 4096;
    mask += (size_t)blockIdx.y * 4096;
    float4 v[4];
    float lmax = -INFINITY;
    #pragma unroll
    for (int c = 0; c < 4; ++c) {
        const int idx = c * 1024 + t * 4;
        v[c] = *reinterpret_cast<const float4*>(&srow[idx]);
        const int4 m4 = *reinterpret_cast<const int4*>(&mask[idx]);
        if (m4.x) v[c].x = -INFINITY;
        if (m4.y) v[c].y = -INFINITY;
        if (m4.z) v[c].z = -INFINITY;
        if (m4.w) v[c].w = -INFINITY;
        lmax = fmaxf(lmax, fmaxf(fmaxf(v[c].x, v[c].y), fmaxf(v[c].z, v[c].w)));
    }
    #pragma unroll
    for (int off = 32; off > 0; off >>= 1)
        lmax = fmaxf(lmax, __shfl_xor(lmax, off));
    __shared__ float redm[4], reds[4];
    if ((t & 63) == 0) redm[t >> 6] = lmax;
    __syncthreads();
    const float bmax = fmaxf(fmaxf(redm[0], redm[1]), fmaxf(redm[2], redm[3]));
    float lsum = 0.f;
    #pragma unroll
    for (int c = 0; c < 4; ++c) {
        v[c].x = __expf(v[c].x - bmax);
        v[c].y = __expf(v[c].y - bmax);
        v[c].z = __expf(v[c].z - bmax);
        v[c].w = __expf(v[c].w - bmax);
        lsum += (v[c].x + v[c].y) + (v[c].z + v[c].w);
    }
    #pragma unroll
    for (int off = 32; off > 0; off >>= 1)
        lsum += __shfl_xor(lsum, off);
    if ((t & 63) == 0) reds[t >> 6] = lsum;
    __syncthreads();
    const float Z = (reds[0] + reds[1]) + (reds[2] + reds[3]);
    const float inv = 1.0f / Z;
    #pragma unroll
    for (int c = 0; c < 4; ++c) {
        const int idx = c * 1024 + t * 4;
        ushort4 o;
        o.x = f2h_u(v[c].x * inv); o.y = f2h_u(v[c].y * inv);
        o.z = f2h_u(v[c].z * inv); o.w = f2h_u(v[c].w * inv);
        *reinterpret_cast<ushort4*>(&prow[idx]) = o;
    }
}

// ---------------------------------------------------------------------------
// 128^2 MFMA GEMM (proven R5-R17): C = A_eff * B_eff^T, B stored [N][K].
// AS/BS in {1,2}: operand hi (+lo). OUTMODE: 0 fp32, 1 f16, 2 f16 pair.
// SWZ: 1D grid with bijective XCD swizzle (z-major chunks per XCD); nx,ny
// give the logical tile grid (nwg must be a multiple of 8).
// ---------------------------------------------------------------------------
template<int TR>
__device__ inline void stage_one(const ushort* __restrict__ g, int ld, int r0,
                                 int k0, ushort* ldsbase, int w, int l)
{
    constexpr int ISS = TR / 64;
    #pragma unroll
    for (int q = 0; q < ISS; ++q) {
        const int idx = (w * ISS + q) * 64 + l;
        const int row = idx >> 2;
        const int gslot = (idx & 3) ^ ((idx >> 3) & 3);
        const ushort* src = g + (size_t)(r0 + row) * ld + k0 + gslot * 8;
        ushort* dst = ldsbase + (size_t)(w * ISS + q) * 512;
        __builtin_amdgcn_global_load_lds(
            (const __attribute__((address_space(1))) void*)src,
            (__attribute__((address_space(3))) void*)dst, 16, 0, 0);
    }
}

template<int BM, int BN, int AS, int BS, int OUTMODE, bool SWZ = false>
__global__ __launch_bounds__(256, 2)
void mfma_gemm_k(const ushort* __restrict__ Ah, const ushort* __restrict__ Al,
                 const ushort* __restrict__ Bh, const ushort* __restrict__ Bl,
                 const float* __restrict__ bias,
                 float* __restrict__ Cf, ushort* __restrict__ Ch,
                 ushort* __restrict__ Cl,
                 int K, int lda, int ldb, int ldc,
                 long long bsA, long long bsB, long long bsC,
                 int nx, int ny)
{
    constexpr int FM = BM / 32, FN = BN / 32;
    constexpr int AU = AS * BM * 32;
    constexpr int TILE_U = AU + BS * BN * 32;
    __shared__ __align__(16) ushort lds[2][TILE_U];

    int bx, by;
    long long zb;
    if constexpr (SWZ) {
        const int nwg = gridDim.x;
        const int q8 = nwg >> 3;
        const int swz = (blockIdx.x & 7) * q8 + (blockIdx.x >> 3);
        const int pt = nx * ny;
        const int z = swz / pt;
        const int r = swz - z * pt;
        by = r / nx; bx = r - by * nx;
        zb = z;
    } else {
        bx = blockIdx.x; by = blockIdx.y; zb = blockIdx.z;
    }

    Ah += zb * bsA; Bh += zb * bsB;
    if constexpr (AS == 2) Al += zb * bsA;
    if constexpr (BS == 2) Bl += zb * bsB;

    const int t = threadIdx.x;
    const int l = t & 63, w = t >> 6;
    const int lr = l & 15, ls = l >> 4;
    const int i0 = by * BM, j0 = bx * BN;
    const int wr = (w >> 1) * (BM / 2), wc = (w & 1) * (BN / 2);
    const int swu = (ls ^ ((lr >> 1) & 3)) * 8;

    f32x4 acc[FM][FN] = {};
    const int nk = K >> 5;

    auto stage = [&](int buf, int kt) {
        const int k0 = kt << 5;
        ushort* base = &lds[buf][0];
        stage_one<BM>(Ah, lda, i0, k0, base, w, l);
        if constexpr (AS == 2) stage_one<BM>(Al, lda, i0, k0, base + BM * 32, w, l);
        stage_one<BN>(Bh, ldb, j0, k0, base + AU, w, l);
        if constexpr (BS == 2) stage_one<BN>(Bl, ldb, j0, k0, base + AU + BN * 32, w, l);
    };

    stage(0, 0);
    for (int kt = 0; kt < nk; ++kt) {
        __syncthreads();
        const int buf = kt & 1;
        if (kt + 1 < nk) stage(buf ^ 1, kt + 1);
        const ushort* base = &lds[buf][0];

        short8 ah[FM], bh[FN];
        #pragma unroll
        for (int fi = 0; fi < FM; ++fi)
            ah[fi] = *reinterpret_cast<const short8*>(
                base + (wr + fi * 16 + lr) * 32 + swu);
        #pragma unroll
        for (int fj = 0; fj < FN; ++fj)
            bh[fj] = *reinterpret_cast<const short8*>(
                base + AU + (wc + fj * 16 + lr) * 32 + swu);

        #pragma unroll
        for (int fi = 0; fi < FM; ++fi)
            #pragma unroll
            for (int fj = 0; fj < FN; ++fj)
                acc[fi][fj] = __builtin_amdgcn_mfma_f32_16x16x32_f16(
                    ah[fi], bh[fj], acc[fi][fj], 0, 0, 0);

        if constexpr (BS == 2) {
            short8 bl[FN];
            #pragma unroll
            for (int fj = 0; fj < FN; ++fj)
                bl[fj] = *reinterpret_cast<const short8*>(
                    base + AU + BN * 32 + (wc + fj * 16 + lr) * 32 + swu);
            #pragma unroll
            for (int fi = 0; fi < FM; ++fi)
                #pragma unroll
                for (int fj = 0; fj < FN; ++fj)
                    acc[fi][fj] = __builtin_amdgcn_mfma_f32_16x16x32_f16(
                        ah[fi], bl[fj], acc[fi][fj], 0, 0, 0);
        }
        if constexpr (AS == 2) {
            short8 al[FM];
            #pragma unroll
            for (int fi = 0; fi < FM; ++fi)
                al[fi] = *reinterpret_cast<const short8*>(
                    base + BM * 32 + (wr + fi * 16 + lr) * 32 + swu);
            #pragma unroll
            for (int fi = 0; fi < FM; ++fi)
                #pragma unroll
                for (int fj = 0; fj < FN; ++fj)
                    acc[fi][fj] = __builtin_amdgcn_mfma_f32_16x16x32_f16(
                        al[fi], bh[fj], acc[fi][fj], 0, 0, 0);
        }
    }

    #pragma unroll
    for (int fj = 0; fj < FN; ++fj) {
        const int gc = j0 + wc + fj * 16 + lr;
        const float bv = bias ? bias[gc] : 0.0f;
        #pragma unroll
        for (int fi = 0; fi < FM; ++fi) {
            const int gr = i0 + wr + fi * 16 + ls * 4;
            #pragma unroll
            for (int r = 0; r < 4; ++r) {
                const float v = acc[fi][fj][r] + bv;
                const size_t o = zb * bsC + (size_t)(gr + r) * ldc + gc;
                if constexpr (OUTMODE == 0) {
                    Cf[o] = v;
                } else if constexpr (OUTMODE == 1) {
                    Ch[o] = f2h_u(v);
                } else {
                    ushort h, lo2; split2h(v, h, lo2);
                    Ch[o] = h;
                    Cl[o] = lo2;
                }
            }
        }
    }
}

// ---------------------------------------------------------------------------
extern "C" void kernel_launch(void* const* d_in, const int* in_sizes, int n_in,
                              void* d_out, int out_size, void* d_ws, size_t ws_size,
                              hipStream_t stream)
{
    (void)in_sizes; (void)n_in; (void)out_size;
    const int NB = 8, LQ = 1024, LI = 4096, D = 1024;
    const long long sQD = (long long)LQ * D;   // 1M
    const long long sID = (long long)LI * D;   // 4M
    const long long sQI = (long long)LQ * LI;  // 4M

    const float* query = (const float*)d_in[0];
    const float* input = (const float*)d_in[1];
    const int* mask = (const int*)d_in[2];   // bool -> int32 on device
    const float* Wq = (const float*)d_in[3];
    const float* bq = (const float*)d_in[4];
    const float* Wk = (const float*)d_in[5];
    /* d_in[6] = bk: cancels in softmax */
    const float* Wo = (const float*)d_in[7];
    const float* bo = (const float*)d_in[8];
    float* out = (float*)d_out;

    dim3 blk(256);

    char* p = (char*)d_ws;
    auto alloc = [&](size_t bytes) {
        char* r = p; p += (bytes + 255) & ~(size_t)255; return r;
    };
    // head buffers
    ushort* qh   = (ushort*)alloc((size_t)NB * sQD * 2);  // query f16
    ushort* WqTh = (ushort*)alloc((size_t)D * D * 2);
    ushort* WqTl = (ushort*)alloc((size_t)D * D * 2);
    ushort* WkTh = (ushort*)alloc((size_t)D * D * 2);
    ushort* WkTl = (ushort*)alloc((size_t)D * D * 2);
    ushort* WTh  = (ushort*)alloc((size_t)D * D * 2);     // W'^T hi/lo
    ushort* WTl  = (ushort*)alloc((size_t)D * D * 2);
    float*  bp   = (float*) alloc((size_t)D * 4);
    ushort* Qh   = (ushort*)alloc((size_t)NB * sQD * 2);  // Q'' f16 (single)
    ushort* Ob   = (ushort*)alloc((size_t)NB * sQD * 2);  // O f16
    ushort* Wob  = (ushort*)alloc((size_t)D * D * 2);     // Wo f16
    char* tail = p;

    // full-batch tail
    ushort* inh = (ushort*)alloc((size_t)NB * sID * 2);   // input f16 [LI][D]
    ushort* VT  = (ushort*)alloc((size_t)NB * sID * 2);   // V^T f16 [D][LI]
    float*  S   = (float*) alloc((size_t)NB * sQI * 4);
    ushort* Pb  = (ushort*)alloc((size_t)NB * sQI * 2);
    const bool full = (size_t)(p - (char*)d_ws) <= ws_size;
    if (!full) {
        p = tail;
        inh = (ushort*)alloc((size_t)sID * 2);
        VT  = (ushort*)alloc((size_t)sID * 2);
        S   = (float*) alloc((size_t)sQI * 4);
        Pb  = (ushort*)alloc((size_t)sQI * 2);
    }

    // ---- head ----
    trans_split_k<<<dim3(32, 32), blk, 0, stream>>>(Wq, WqTh, WqTl, D, D);
    trans_split_k<<<dim3(32, 32), blk, 0, stream>>>(Wk, WkTh, WkTl, D, D);
    bias_proj_k<<<dim3(4), blk, 0, stream>>>(bq, Wk, bp);
    // W'^T = Wk^T @ (Wq^T)^T, split-2 both sides, hi/lo out
    mfma_gemm_k<64, 64, 2, 2, 2><<<dim3(16, 16, 1), blk, 0, stream>>>(
        WkTh, WkTl, WqTh, WqTl, nullptr, nullptr, WTh, WTl, D, D, D, D, 0, 0, 0, 0, 0);
    split_k<<<dim3(2048), blk, 0, stream>>>(query, qh, nullptr, NB * (int)sQD / 4);
    split_k<<<dim3(1024), blk, 0, stream>>>(Wo, Wob, nullptr, D * D / 4);
    // Q'' = query @ W' + b'  (A single, B hi/lo; f16 out)
    mfma_gemm_k<128, 128, 1, 2, 1><<<dim3(D / 128, NB * LQ / 128, 1), blk, 0, stream>>>(
        qh, nullptr, WTh, WTl, bp, nullptr, Qh, nullptr, D, D, D, D, 0, 0, 0, 0, 0);

    if (full) {
        prep_input_k<<<dim3(D / 32, LI / 32, NB), blk, 0, stream>>>(
            input, inh, VT, LI, D, sID);
        // S = Q'' @ input^T  (single f16, K=1024; fp32 out; XCD-swizzled)
        mfma_gemm_k<128, 128, 1, 1, 0, true><<<dim3((LI/128)*(LQ/128)*NB), blk, 0, stream>>>(
            Qh, nullptr, inh, nullptr, nullptr, S, nullptr, nullptr,
            D, D, D, LI, sQD, sID, sQI, LI / 128, LQ / 128);
        softmax_f16_k<<<dim3(LQ, NB), blk, 0, stream>>>(S, mask, Pb);
        // O = P @ V  (plain f16; XCD-swizzled)
        mfma_gemm_k<128, 128, 1, 1, 1, true><<<dim3((D/128)*(LQ/128)*NB), blk, 0, stream>>>(
            Pb, nullptr, VT, nullptr, nullptr, nullptr, Ob, nullptr,
            LI, LI, LI, D, sQI, sID, sQD, D / 128, LQ / 128);
    } else {
        for (int b = 0; b < NB; ++b) {
            const float* in_b = input + (size_t)b * sID;
            prep_input_k<<<dim3(D / 32, LI / 32, 1), blk, 0, stream>>>(
                in_b, inh, VT, LI, D, 0);
            mfma_gemm_k<128, 128, 1, 1, 0><<<dim3(LI / 128, LQ / 128, 1), blk, 0, stream>>>(
                Qh + (size_t)b * sQD, nullptr, inh, nullptr, nullptr, S, nullptr, nullptr,
                D, D, D, LI, 0, 0, 0, 0, 0);
            softmax_f16_k<<<dim3(LQ, 1), blk, 0, stream>>>(S, mask + (size_t)b * LI, Pb);
            mfma_gemm_k<128, 128, 1, 1, 1><<<dim3(D / 128, LQ / 128, 1), blk, 0, stream>>>(
                Pb, nullptr, VT, nullptr, nullptr, nullptr,
                Ob + (size_t)b * sQD, nullptr, LI, LI, LI, D, 0, 0, 0, 0, 0);
        }
    }
    // out = O @ Wo^T + bo (fp32 out)
    mfma_gemm_k<128, 128, 1, 1, 0><<<dim3(D / 128, NB * LQ / 128, 1), blk, 0, stream>>>(
        Ob, nullptr, Wob, nullptr, bo, out, nullptr, nullptr, D, D, D, D, 0, 0, 0, 0, 0);
}

// Round 20
// 452.285 us; speedup vs baseline: 1.0765x; 1.0168x over previous
//
#include <hip/hip_runtime.h>
#include <math.h>

// CrossAttention (N=8, Lq=1024, Lk=4096, D=1024), fp32 in/out.
// scores = Q''*input^T (+row const); Q'' = query*(Wq^T*Wk) + bq*Wk; bk cancels.
// V = unprojected input. out = (P*V)*Wo^T + bo.
// R14: score path single-f16 (absmax 0.0898 < 0.1006).
// R17: T1 bijective XCD swizzle on S/PV. R19: KU=2 reverted (regression).
// R20: swizzle extended to Q''-proj and out-proj (nwg=512, multiple of 8).
// S fp32 (f16-S would triple the error budget). P/V/O/Wo f16.

using short8 = __attribute__((ext_vector_type(8))) short;
using f32x4  = __attribute__((ext_vector_type(4))) float;

__device__ inline ushort f2h_u(float f) {
    _Float16 h = (_Float16)f;
    return __builtin_bit_cast(ushort, h);
}
__device__ inline float h2f(ushort u) {
    return (float)__builtin_bit_cast(_Float16, u);
}
__device__ inline void split2h(float x, ushort& h, ushort& l) {
    const ushort hu = f2h_u(x);
    h = hu;
    l = f2h_u(x - h2f(hu));
}

// b'[j] = sum_d bq[d] * Wk[d][j]
__global__ __launch_bounds__(256)
void bias_proj_k(const float* __restrict__ bq, const float* __restrict__ Wk,
                 float* __restrict__ bp)
{
    const int j = blockIdx.x * 256 + threadIdx.x;
    float s = 0.f;
    for (int d = 0; d < 1024; ++d) s = fmaf(bq[d], Wk[d * 1024 + j], s);
    bp[j] = s;
}

// fp32 -> f16 hi (+optional lo), grid-stride over float4s
__global__ __launch_bounds__(256)
void split_k(const float* __restrict__ x, ushort* __restrict__ hi,
             ushort* __restrict__ lo, int n4)
{
    for (int i = blockIdx.x * 256 + threadIdx.x; i < n4; i += gridDim.x * 256) {
        const float4 v = reinterpret_cast<const float4*>(x)[i];
        ushort4 h, l;
        split2h(v.x, h.x, l.x); split2h(v.y, h.y, l.y);
        split2h(v.z, h.z, l.z); split2h(v.w, h.w, l.w);
        reinterpret_cast<ushort4*>(hi)[i] = h;
        if (lo) reinterpret_cast<ushort4*>(lo)[i] = l;
    }
}

// out[c][r] = in[r][c] with f16 hi/lo split. grid (C/32, R/32).
__global__ __launch_bounds__(256)
void trans_split_k(const float* __restrict__ in, ushort* __restrict__ oh,
                   ushort* __restrict__ ol, int R, int C)
{
    __shared__ float ts[32][33];
    const int t = threadIdx.x, tx = t & 31, tg = t >> 5;
    const int r0 = blockIdx.y * 32, c0 = blockIdx.x * 32;
    #pragma unroll
    for (int i = 0; i < 4; ++i) {
        const int r = tg * 4 + i;
        ts[r][tx] = in[(size_t)(r0 + r) * C + c0 + tx];
    }
    __syncthreads();
    #pragma unroll
    for (int i = 0; i < 4; ++i) {
        const int c = tg * 4 + i;
        ushort h, l; split2h(ts[tx][c], h, l);
        const size_t o = (size_t)(c0 + c) * R + r0 + tx;
        oh[o] = h;
        if (ol) ol[o] = l;
    }
}

// Fused: read input [LI][D] fp32 once -> ih f16 [LI][D] + VT f16 [D][LI].
// grid (D/32, LI/32, NB), block 256.
__global__ __launch_bounds__(256)
void prep_input_k(const float* __restrict__ in, ushort* __restrict__ ih,
                  ushort* __restrict__ vt, int LI, int D, long long bs)
{
    __shared__ float ts[32][33];
    const int t = threadIdx.x;
    const int tx8 = t & 7, ty = t >> 3;
    const int r0 = blockIdx.y * 32, c0 = blockIdx.x * 32;
    const long long z = blockIdx.z;
    in += z * bs; ih += z * bs; vt += z * bs;

    const float4 v = *reinterpret_cast<const float4*>(
        &in[(size_t)(r0 + ty) * D + c0 + tx8 * 4]);
    ushort4 h;
    h.x = f2h_u(v.x); h.y = f2h_u(v.y); h.z = f2h_u(v.z); h.w = f2h_u(v.w);
    *reinterpret_cast<ushort4*>(&ih[(size_t)(r0 + ty) * D + c0 + tx8 * 4]) = h;
    ts[ty][tx8 * 4 + 0] = v.x; ts[ty][tx8 * 4 + 1] = v.y;
    ts[ty][tx8 * 4 + 2] = v.z; ts[ty][tx8 * 4 + 3] = v.w;
    __syncthreads();
    const int tx = t & 31, tg = t >> 5;
    #pragma unroll
    for (int i = 0; i < 4; ++i) {
        const int c = tg * 4 + i;
        vt[(size_t)(c0 + c) * LI + r0 + tx] = f2h_u(ts[tx][c]);
    }
}

// masked softmax over 4096-wide fp32 rows -> f16 P. grid (LQ, NB).
__global__ __launch_bounds__(256)
void softmax_f16_k(const float* __restrict__ S, const int* __restrict__ mask,
                   ushort* __restrict__ P)
{
    const int t = threadIdx.x;
    const size_t row = (size_t)blockIdx.y * gridDim.x + blockIdx.x;
    const float* srow = S + row * 4096;
    ushort* prow = P + row * 4096;
    mask += (size_t)blockIdx.y * 4096;
    float4 v[4];
    float lmax = -INFINITY;
    #pragma unroll
    for (int c = 0; c < 4; ++c) {
        const int idx = c * 1024 + t * 4;
        v[c] = *reinterpret_cast<const float4*>(&srow[idx]);
        const int4 m4 = *reinterpret_cast<const int4*>(&mask[idx]);
        if (m4.x) v[c].x = -INFINITY;
        if (m4.y) v[c].y = -INFINITY;
        if (m4.z) v[c].z = -INFINITY;
        if (m4.w) v[c].w = -INFINITY;
        lmax = fmaxf(lmax, fmaxf(fmaxf(v[c].x, v[c].y), fmaxf(v[c].z, v[c].w)));
    }
    #pragma unroll
    for (int off = 32; off > 0; off >>= 1)
        lmax = fmaxf(lmax, __shfl_xor(lmax, off));
    __shared__ float redm[4], reds[4];
    if ((t & 63) == 0) redm[t >> 6] = lmax;
    __syncthreads();
    const float bmax = fmaxf(fmaxf(redm[0], redm[1]), fmaxf(redm[2], redm[3]));
    float lsum = 0.f;
    #pragma unroll
    for (int c = 0; c < 4; ++c) {
        v[c].x = __expf(v[c].x - bmax);
        v[c].y = __expf(v[c].y - bmax);
        v[c].z = __expf(v[c].z - bmax);
        v[c].w = __expf(v[c].w - bmax);
        lsum += (v[c].x + v[c].y) + (v[c].z + v[c].w);
    }
    #pragma unroll
    for (int off = 32; off > 0; off >>= 1)
        lsum += __shfl_xor(lsum, off);
    if ((t & 63) == 0) reds[t >> 6] = lsum;
    __syncthreads();
    const float Z = (reds[0] + reds[1]) + (reds[2] + reds[3]);
    const float inv = 1.0f / Z;
    #pragma unroll
    for (int c = 0; c < 4; ++c) {
        const int idx = c * 1024 + t * 4;
        ushort4 o;
        o.x = f2h_u(v[c].x * inv); o.y = f2h_u(v[c].y * inv);
        o.z = f2h_u(v[c].z * inv); o.w = f2h_u(v[c].w * inv);
        *reinterpret_cast<ushort4*>(&prow[idx]) = o;
    }
}

// ---------------------------------------------------------------------------
// 128^2 MFMA GEMM (proven R5-R19): C = A_eff * B_eff^T, B stored [N][K].
// AS/BS in {1,2}: operand hi (+lo). OUTMODE: 0 fp32, 1 f16, 2 f16 pair.
// SWZ: 1D grid with bijective XCD swizzle (nwg % 8 == 0).
// ---------------------------------------------------------------------------
template<int TR>
__device__ inline void stage_one(const ushort* __restrict__ g, int ld, int r0,
                                 int k0, ushort* ldsbase, int w, int l)
{
    constexpr int ISS = TR / 64;
    #pragma unroll
    for (int q = 0; q < ISS; ++q) {
        const int idx = (w * ISS + q) * 64 + l;
        const int row = idx >> 2;
        const int gslot = (idx & 3) ^ ((idx >> 3) & 3);
        const ushort* src = g + (size_t)(r0 + row) * ld + k0 + gslot * 8;
        ushort* dst = ldsbase + (size_t)(w * ISS + q) * 512;
        __builtin_amdgcn_global_load_lds(
            (const __attribute__((address_space(1))) void*)src,
            (__attribute__((address_space(3))) void*)dst, 16, 0, 0);
    }
}

template<int BM, int BN, int AS, int BS, int OUTMODE, bool SWZ = false>
__global__ __launch_bounds__(256, 2)
void mfma_gemm_k(const ushort* __restrict__ Ah, const ushort* __restrict__ Al,
                 const ushort* __restrict__ Bh, const ushort* __restrict__ Bl,
                 const float* __restrict__ bias,
                 float* __restrict__ Cf, ushort* __restrict__ Ch,
                 ushort* __restrict__ Cl,
                 int K, int lda, int ldb, int ldc,
                 long long bsA, long long bsB, long long bsC,
                 int nx, int ny)
{
    constexpr int FM = BM / 32, FN = BN / 32;
    constexpr int AU = AS * BM * 32;
    constexpr int TILE_U = AU + BS * BN * 32;
    __shared__ __align__(16) ushort lds[2][TILE_U];

    int bx, by;
    long long zb;
    if constexpr (SWZ) {
        const int nwg = gridDim.x;
        const int q8 = nwg >> 3;
        const int swz = (blockIdx.x & 7) * q8 + (blockIdx.x >> 3);
        const int pt = nx * ny;
        const int z = swz / pt;
        const int r = swz - z * pt;
        by = r / nx; bx = r - by * nx;
        zb = z;
    } else {
        bx = blockIdx.x; by = blockIdx.y; zb = blockIdx.z;
    }

    Ah += zb * bsA; Bh += zb * bsB;
    if constexpr (AS == 2) Al += zb * bsA;
    if constexpr (BS == 2) Bl += zb * bsB;

    const int t = threadIdx.x;
    const int l = t & 63, w = t >> 6;
    const int lr = l & 15, ls = l >> 4;
    const int i0 = by * BM, j0 = bx * BN;
    const int wr = (w >> 1) * (BM / 2), wc = (w & 1) * (BN / 2);
    const int swu = (ls ^ ((lr >> 1) & 3)) * 8;

    f32x4 acc[FM][FN] = {};
    const int nk = K >> 5;

    auto stage = [&](int buf, int kt) {
        const int k0 = kt << 5;
        ushort* base = &lds[buf][0];
        stage_one<BM>(Ah, lda, i0, k0, base, w, l);
        if constexpr (AS == 2) stage_one<BM>(Al, lda, i0, k0, base + BM * 32, w, l);
        stage_one<BN>(Bh, ldb, j0, k0, base + AU, w, l);
        if constexpr (BS == 2) stage_one<BN>(Bl, ldb, j0, k0, base + AU + BN * 32, w, l);
    };

    stage(0, 0);
    for (int kt = 0; kt < nk; ++kt) {
        __syncthreads();
        const int buf = kt & 1;
        if (kt + 1 < nk) stage(buf ^ 1, kt + 1);
        const ushort* base = &lds[buf][0];

        short8 ah[FM], bh[FN];
        #pragma unroll
        for (int fi = 0; fi < FM; ++fi)
            ah[fi] = *reinterpret_cast<const short8*>(
                base + (wr + fi * 16 + lr) * 32 + swu);
        #pragma unroll
        for (int fj = 0; fj < FN; ++fj)
            bh[fj] = *reinterpret_cast<const short8*>(
                base + AU + (wc + fj * 16 + lr) * 32 + swu);

        #pragma unroll
        for (int fi = 0; fi < FM; ++fi)
            #pragma unroll
            for (int fj = 0; fj < FN; ++fj)
                acc[fi][fj] = __builtin_amdgcn_mfma_f32_16x16x32_f16(
                    ah[fi], bh[fj], acc[fi][fj], 0, 0, 0);

        if constexpr (BS == 2) {
            short8 bl[FN];
            #pragma unroll
            for (int fj = 0; fj < FN; ++fj)
                bl[fj] = *reinterpret_cast<const short8*>(
                    base + AU + BN * 32 + (wc + fj * 16 + lr) * 32 + swu);
            #pragma unroll
            for (int fi = 0; fi < FM; ++fi)
                #pragma unroll
                for (int fj = 0; fj < FN; ++fj)
                    acc[fi][fj] = __builtin_amdgcn_mfma_f32_16x16x32_f16(
                        ah[fi], bl[fj], acc[fi][fj], 0, 0, 0);
        }
        if constexpr (AS == 2) {
            short8 al[FM];
            #pragma unroll
            for (int fi = 0; fi < FM; ++fi)
                al[fi] = *reinterpret_cast<const short8*>(
                    base + BM * 32 + (wr + fi * 16 + lr) * 32 + swu);
            #pragma unroll
            for (int fi = 0; fi < FM; ++fi)
                #pragma unroll
                for (int fj = 0; fj < FN; ++fj)
                    acc[fi][fj] = __builtin_amdgcn_mfma_f32_16x16x32_f16(
                        al[fi], bh[fj], acc[fi][fj], 0, 0, 0);
        }
    }

    #pragma unroll
    for (int fj = 0; fj < FN; ++fj) {
        const int gc = j0 + wc + fj * 16 + lr;
        const float bv = bias ? bias[gc] : 0.0f;
        #pragma unroll
        for (int fi = 0; fi < FM; ++fi) {
            const int gr = i0 + wr + fi * 16 + ls * 4;
            #pragma unroll
            for (int r = 0; r < 4; ++r) {
                const float v = acc[fi][fj][r] + bv;
                const size_t o = zb * bsC + (size_t)(gr + r) * ldc + gc;
                if constexpr (OUTMODE == 0) {
                    Cf[o] = v;
                } else if constexpr (OUTMODE == 1) {
                    Ch[o] = f2h_u(v);
                } else {
                    ushort h, lo2; split2h(v, h, lo2);
                    Ch[o] = h;
                    Cl[o] = lo2;
                }
            }
        }
    }
}

// ---------------------------------------------------------------------------
extern "C" void kernel_launch(void* const* d_in, const int* in_sizes, int n_in,
                              void* d_out, int out_size, void* d_ws, size_t ws_size,
                              hipStream_t stream)
{
    (void)in_sizes; (void)n_in; (void)out_size;
    const int NB = 8, LQ = 1024, LI = 4096, D = 1024;
    const long long sQD = (long long)LQ * D;   // 1M
    const long long sID = (long long)LI * D;   // 4M
    const long long sQI = (long long)LQ * LI;  // 4M

    const float* query = (const float*)d_in[0];
    const float* input = (const float*)d_in[1];
    const int* mask = (const int*)d_in[2];   // bool -> int32 on device
    const float* Wq = (const float*)d_in[3];
    const float* bq = (const float*)d_in[4];
    const float* Wk = (const float*)d_in[5];
    /* d_in[6] = bk: cancels in softmax */
    const float* Wo = (const float*)d_in[7];
    const float* bo = (const float*)d_in[8];
    float* out = (float*)d_out;

    dim3 blk(256);

    char* p = (char*)d_ws;
    auto alloc = [&](size_t bytes) {
        char* r = p; p += (bytes + 255) & ~(size_t)255; return r;
    };
    // head buffers
    ushort* qh   = (ushort*)alloc((size_t)NB * sQD * 2);  // query f16
    ushort* WqTh = (ushort*)alloc((size_t)D * D * 2);
    ushort* WqTl = (ushort*)alloc((size_t)D * D * 2);
    ushort* WkTh = (ushort*)alloc((size_t)D * D * 2);
    ushort* WkTl = (ushort*)alloc((size_t)D * D * 2);
    ushort* WTh  = (ushort*)alloc((size_t)D * D * 2);     // W'^T hi/lo
    ushort* WTl  = (ushort*)alloc((size_t)D * D * 2);
    float*  bp   = (float*) alloc((size_t)D * 4);
    ushort* Qh   = (ushort*)alloc((size_t)NB * sQD * 2);  // Q'' f16 (single)
    ushort* Ob   = (ushort*)alloc((size_t)NB * sQD * 2);  // O f16
    ushort* Wob  = (ushort*)alloc((size_t)D * D * 2);     // Wo f16
    char* tail = p;

    // full-batch tail
    ushort* inh = (ushort*)alloc((size_t)NB * sID * 2);   // input f16 [LI][D]
    ushort* VT  = (ushort*)alloc((size_t)NB * sID * 2);   // V^T f16 [D][LI]
    float*  S   = (float*) alloc((size_t)NB * sQI * 4);
    ushort* Pb  = (ushort*)alloc((size_t)NB * sQI * 2);
    const bool full = (size_t)(p - (char*)d_ws) <= ws_size;
    if (!full) {
        p = tail;
        inh = (ushort*)alloc((size_t)sID * 2);
        VT  = (ushort*)alloc((size_t)sID * 2);
        S   = (float*) alloc((size_t)sQI * 4);
        Pb  = (ushort*)alloc((size_t)sQI * 2);
    }

    // ---- head ----
    trans_split_k<<<dim3(32, 32), blk, 0, stream>>>(Wq, WqTh, WqTl, D, D);
    trans_split_k<<<dim3(32, 32), blk, 0, stream>>>(Wk, WkTh, WkTl, D, D);
    bias_proj_k<<<dim3(4), blk, 0, stream>>>(bq, Wk, bp);
    // W'^T = Wk^T @ (Wq^T)^T, split-2 both sides, hi/lo out
    mfma_gemm_k<64, 64, 2, 2, 2><<<dim3(16, 16, 1), blk, 0, stream>>>(
        WkTh, WkTl, WqTh, WqTl, nullptr, nullptr, WTh, WTl, D, D, D, D, 0, 0, 0, 0, 0);
    split_k<<<dim3(2048), blk, 0, stream>>>(query, qh, nullptr, NB * (int)sQD / 4);
    split_k<<<dim3(1024), blk, 0, stream>>>(Wo, Wob, nullptr, D * D / 4);
    // Q'' = query @ W' + b'  (A single, B hi/lo; f16 out; XCD-swizzled)
    mfma_gemm_k<128, 128, 1, 2, 1, true><<<dim3((D/128)*(NB*LQ/128)), blk, 0, stream>>>(
        qh, nullptr, WTh, WTl, bp, nullptr, Qh, nullptr, D, D, D, D,
        0, 0, 0, D / 128, NB * LQ / 128);

    if (full) {
        prep_input_k<<<dim3(D / 32, LI / 32, NB), blk, 0, stream>>>(
            input, inh, VT, LI, D, sID);
        // S = Q'' @ input^T  (single f16, K=1024; fp32 out; XCD-swizzled)
        mfma_gemm_k<128, 128, 1, 1, 0, true><<<dim3((LI/128)*(LQ/128)*NB), blk, 0, stream>>>(
            Qh, nullptr, inh, nullptr, nullptr, S, nullptr, nullptr,
            D, D, D, LI, sQD, sID, sQI, LI / 128, LQ / 128);
        softmax_f16_k<<<dim3(LQ, NB), blk, 0, stream>>>(S, mask, Pb);
        // O = P @ V  (plain f16; XCD-swizzled)
        mfma_gemm_k<128, 128, 1, 1, 1, true><<<dim3((D/128)*(LQ/128)*NB), blk, 0, stream>>>(
            Pb, nullptr, VT, nullptr, nullptr, nullptr, Ob, nullptr,
            LI, LI, LI, D, sQI, sID, sQD, D / 128, LQ / 128);
    } else {
        for (int b = 0; b < NB; ++b) {
            const float* in_b = input + (size_t)b * sID;
            prep_input_k<<<dim3(D / 32, LI / 32, 1), blk, 0, stream>>>(
                in_b, inh, VT, LI, D, 0);
            mfma_gemm_k<128, 128, 1, 1, 0><<<dim3(LI / 128, LQ / 128, 1), blk, 0, stream>>>(
                Qh + (size_t)b * sQD, nullptr, inh, nullptr, nullptr, S, nullptr, nullptr,
                D, D, D, LI, 0, 0, 0, 0, 0);
            softmax_f16_k<<<dim3(LQ, 1), blk, 0, stream>>>(S, mask + (size_t)b * LI, Pb);
            mfma_gemm_k<128, 128, 1, 1, 1><<<dim3(D / 128, LQ / 128, 1), blk, 0, stream>>>(
                Pb, nullptr, VT, nullptr, nullptr, nullptr,
                Ob + (size_t)b * sQD, nullptr, LI, LI, LI, D, 0, 0, 0, 0, 0);
        }
    }
    // out = O @ Wo^T + bo (fp32 out; XCD-swizzled)
    mfma_gemm_k<128, 128, 1, 1, 0, true><<<dim3((D/128)*(NB*LQ/128)), blk, 0, stream>>>(
        Ob, nullptr, Wob, nullptr, bo, out, nullptr, nullptr, D, D, D, D,
        0, 0, 0, D / 128, NB * LQ / 128);
}